// Round 1
// baseline (36.587 us; speedup 1.0000x reference)
//
#include <hip/hip_runtime.h>

// Segment-mean over a static per-sequence pattern:
//   K=99 rows/sequence, M=64 cols, b=8192 sequences.
//   row k: k<49 -> seg k%3 ; k==49 -> dropped ; k>49 -> seg 3+(k-50)%3
//   counts per segment: {17,16,16,17,16,16}
//   out[seq][s*64 + c] = mean over rows of segment s.
// Memory-bound: 207.6 MB read + 12.6 MB write -> ~35 us at 6.3 TB/s.

__device__ __forceinline__ float4 f4add(float4 a, float4 b) {
    return make_float4(a.x + b.x, a.y + b.y, a.z + b.z, a.w + b.w);
}

__global__ __launch_bounds__(256) void seg_mean_kernel(
        const float* __restrict__ in, float* __restrict__ out) {
    const int tid = threadIdx.x;
    const int c4  = tid & 15;   // float4 column group (16 x 4 floats = 64 cols)
    const int r   = tid >> 4;   // row group 0..15 ; thread handles rows r+16j
    const long long seq = blockIdx.x;

    const float4* __restrict__ base =
        reinterpret_cast<const float4*>(in) + seq * (99LL * 16) + c4;

    const float4 z = make_float4(0.f, 0.f, 0.f, 0.f);
    // Phase-rotated accumulators: p = r%3.
    //  AL[t] holds left  segment (p+t)%3
    //  AR[u] holds right segment 3+(p+u)%3
    // Left rows k=r+16j (j=0..2, plus k=48): s = (p+j)%3      -> t = j%3
    // Right rows:        s-3 = (k-50)%3 = (p+j+1)%3           -> u = (j+1)%3
    float4 AL0 = z, AL1 = z, AL2 = z, AR0 = z, AR1 = z, AR2 = z;

    // Issue all global loads up front (independent -> max MLP).
    float4 v0 = base[(r + 0)  * 16];   // k in [0,16)   left, t=0
    float4 v1 = base[(r + 16) * 16];   // k in [16,32)  left, t=1
    float4 v2 = base[(r + 32) * 16];   // k in [32,48)  left, t=2
    float4 v3 = base[(r + 48) * 16];   // k in [48,64): r==0 left t=0; r==1 dropped; r>=2 right u=1
    float4 v4 = base[(r + 64) * 16];   // right, u=2
    float4 v5 = base[(r + 80) * 16];   // right, u=0
    float4 v6 = z;
    if (r < 3) v6 = base[(r + 96) * 16];   // k=96..98, right, u=1

    AL0 = f4add(AL0, v0);
    AL1 = f4add(AL1, v1);
    AL2 = f4add(AL2, v2);
    if (r == 0) AL0 = f4add(AL0, v3);   // k=48, seg 0 (p=0)
    if (r >= 2) AR1 = f4add(AR1, v3);   // k=50..63
    AR2 = f4add(AR2, v4);
    AR0 = f4add(AR0, v5);
    if (r < 3) AR1 = f4add(AR1, v6);

    // Un-rotate at LDS-write time (runtime LDS address, static registers).
    __shared__ float4 lds[16][6][16];   // 24 KB
    const int p  = r % 3;
    int p1 = p + 1; if (p1 == 3) p1 = 0;
    int p2 = p1 + 1; if (p2 == 3) p2 = 0;
    lds[r][p      ][c4] = AL0;
    lds[r][p1     ][c4] = AL1;
    lds[r][p2     ][c4] = AL2;
    lds[r][3 + p  ][c4] = AR0;
    lds[r][3 + p1 ][c4] = AR1;
    lds[r][3 + p2 ][c4] = AR2;
    __syncthreads();

    // Final reduce across the 16 row groups: 96 threads, one float4 each.
    if (tid < 96) {
        const int s = tid >> 4;   // segment 0..5
        const int c = tid & 15;   // float4 column group
        float4 sum = z;
        #pragma unroll
        for (int rr = 0; rr < 16; ++rr) sum = f4add(sum, lds[rr][s][c]);
        const float iv = (s == 0 || s == 3) ? (1.0f / 17.0f) : (1.0f / 16.0f);
        float4 res = make_float4(sum.x * iv, sum.y * iv, sum.z * iv, sum.w * iv);
        reinterpret_cast<float4*>(out)[seq * 96 + tid] = res;
    }
}

extern "C" void kernel_launch(void* const* d_in, const int* in_sizes, int n_in,
                              void* d_out, int out_size, void* d_ws, size_t ws_size,
                              hipStream_t stream) {
    const float* in = (const float*)d_in[0];
    float* out = (float*)d_out;
    const int b = in_sizes[0] / (99 * 64);   // 8192 sequences
    seg_mean_kernel<<<b, 256, 0, stream>>>(in, out);
}